// Round 10
// baseline (227.595 us; speedup 1.0000x reference)
//
#include <hip/hip_runtime.h>

#define B 8
#define C 256
#define P1 2048
#define P2 4096
#define CQ 32

typedef _Float16 h8 __attribute__((ext_vector_type(8)));
typedef _Float16 h4 __attribute__((ext_vector_type(4)));
typedef float f4 __attribute__((ext_vector_type(4)));

#define MFMA16(a, b, c) __builtin_amdgcn_mfma_f32_16x16x32_f16(a, b, c, 0, 0, 0)

// ---------------------------------------------------------------------------
// Convert weights to f16 hi/lo once. grid 32 x 256.
// ---------------------------------------------------------------------------
__global__ void prep_w(const float* __restrict__ Wq, const float* __restrict__ Wk,
                       const float* __restrict__ Wv,
                       _Float16* __restrict__ Wqh, _Float16* __restrict__ Wql,
                       _Float16* __restrict__ Wkh, _Float16* __restrict__ Wkl,
                       _Float16* __restrict__ Wvh) {
    const int i = blockIdx.x * 256 + threadIdx.x;
    if (i < CQ * C) {
        float a = Wq[i]; _Float16 h = (_Float16)a;
        Wqh[i] = h; Wql[i] = (_Float16)(a - (float)h);
        float b2 = Wk[i]; _Float16 h2 = (_Float16)b2;
        Wkh[i] = h2; Wkl[i] = (_Float16)(b2 - (float)h2);
    }
    for (int j = i; j < C * C; j += 32 * 256)
        Wvh[j] = (_Float16)Wv[j];
}

// ---------------------------------------------------------------------------
// prep_qkv: merged prep1+prep2. blockIdx.y < 64 -> x1 tile: q (hi/lo) + v
// (hi, single-pass). blockIdx.y >= 64 -> x2 tile: k (hi/lo).
// NEW: x is converted to hi/lo f16 ONCE at staging into two LDS arrays
// [32][264] (pad 264 -> b128-aligned rows, conflict-free staging writes and
// fragment reads). The ks loop reads bh/bl as single ds_read_b128 each —
// replaces 8 b32 reads + ~24 cvt VALU per ks per thread, and removes the 2x
// conversion duplication across the two c-half waves. Numerically identical.
// grid (B, 192), block 256.
// ---------------------------------------------------------------------------
__global__ __launch_bounds__(256) void prep_qkv(
        const float* __restrict__ x1, const float* __restrict__ x2,
        const _Float16* __restrict__ Wqh, const _Float16* __restrict__ Wql,
        const _Float16* __restrict__ Wvh,
        const _Float16* __restrict__ Wkh, const _Float16* __restrict__ Wkl,
        const float* __restrict__ bq, const float* __restrict__ bv,
        const float* __restrict__ bk,
        _Float16* __restrict__ qhw, _Float16* __restrict__ qlw,
        _Float16* __restrict__ vhw,
        _Float16* __restrict__ khw, _Float16* __restrict__ klw) {
    __shared__ _Float16 xh[32][264];
    __shared__ _Float16 xl[32][264];
    const int t = threadIdx.x;
    const int b = blockIdx.x;
    const int y = blockIdx.y;
    const bool is1 = (y < P1 / 32);
    const int p0 = (is1 ? y : y - P1 / 32) * 32;
    const float* xb = is1 ? x1 + (size_t)b * C * P1 : x2 + (size_t)b * C * P2;
    const int ps = is1 ? P1 : P2;

    {   // stage [256c][32p] -> LDS hi/lo [p][c]; b128 loads (4 consecutive p)
        const int pl4 = t & 7, cb = t >> 3;
#pragma unroll
        for (int i = 0; i < 8; ++i) {
            const int c = cb + i * 32;
            f4 v = *(const f4*)&xb[(size_t)c * ps + p0 + pl4 * 4];
#pragma unroll
            for (int r = 0; r < 4; ++r) {
                float xv = v[r];
                _Float16 hh = (_Float16)xv;
                xh[pl4 * 4 + r][c] = hh;
                xl[pl4 * 4 + r][c] = (_Float16)(xv - (float)hh);
            }
        }
    }
    __syncthreads();

    const int w = t >> 6, lane = t & 63, ln = lane & 15, quad = lane >> 4;
    const int nh = w & 1, ch = w >> 1;
    const int prow = nh * 16 + ln;

    if (is1) {
        // ---- q (3-pass hi/lo) + v (1-pass hi) ----
        f4 accv[8];
#pragma unroll
        for (int mt = 0; mt < 8; ++mt) accv[mt] = (f4){0.f, 0.f, 0.f, 0.f};
        f4 accq = {0.f, 0.f, 0.f, 0.f};

        for (int ks = 0; ks < 8; ++ks) {
            const int c0 = ks * 32 + quad * 8;
            h8 bh = *(const h8*)&xh[prow][c0];
            h8 bl = *(const h8*)&xl[prow][c0];
#pragma unroll
            for (int mt = 0; mt < 8; ++mt) {
                h8 a = *(const h8*)&Wvh[(size_t)((ch * 8 + mt) * 16 + ln) * C + c0];
                accv[mt] = MFMA16(a, bh, accv[mt]);
            }
            {
                h8 aqh = *(const h8*)&Wqh[(size_t)(ch * 16 + ln) * C + c0];
                h8 aql = *(const h8*)&Wql[(size_t)(ch * 16 + ln) * C + c0];
                accq = MFMA16(aql, bh, accq);
                accq = MFMA16(aqh, bl, accq);
                accq = MFMA16(aqh, bh, accq);
            }
        }
        // v epilogue: C-frag col=p(ln), row=c(quad*4+r)
#pragma unroll
        for (int mt = 0; mt < 8; ++mt) {
            int cb2 = (ch * 8 + mt) * 16 + quad * 4;
            f4 bvv = *(const f4*)&bv[cb2];
#pragma unroll
            for (int r = 0; r < 4; ++r)
                vhw[((size_t)b * C + cb2 + r) * P1 + p0 + prow] =
                    (_Float16)(accv[mt][r] + bvv[r]);
        }
        // q epilogue: hi/lo pack
        {
            int ob = ch * 16 + quad * 4;
            f4 bqv = *(const f4*)&bq[ob];
            h4 hv, lv;
#pragma unroll
            for (int r = 0; r < 4; ++r) {
                float val = accq[r] + bqv[r];
                _Float16 hh = (_Float16)val;
                hv[r] = hh; lv[r] = (_Float16)(val - (float)hh);
            }
            size_t row = ((size_t)b * P1 + p0 + prow) * CQ + ob;
            *(h4*)(qhw + row) = hv;
            *(h4*)(qlw + row) = lv;
        }
    } else {
        // ---- k (3-pass hi/lo) ----
        f4 accq = {0.f, 0.f, 0.f, 0.f};
        for (int ks = 0; ks < 8; ++ks) {
            const int c0 = ks * 32 + quad * 8;
            h8 bh = *(const h8*)&xh[prow][c0];
            h8 bl = *(const h8*)&xl[prow][c0];
            h8 akh = *(const h8*)&Wkh[(size_t)(ch * 16 + ln) * C + c0];
            h8 akl = *(const h8*)&Wkl[(size_t)(ch * 16 + ln) * C + c0];
            accq = MFMA16(akl, bh, accq);
            accq = MFMA16(akh, bl, accq);
            accq = MFMA16(akh, bh, accq);
        }
        {
            int ob = ch * 16 + quad * 4;
            f4 bkv = *(const f4*)&bk[ob];
            h4 hv, lv;
#pragma unroll
            for (int r = 0; r < 4; ++r) {
                float val = accq[r] + bkv[r];
                _Float16 hh = (_Float16)val;
                hv[r] = hh; lv[r] = (_Float16)(val - (float)hh);
            }
            size_t row = ((size_t)b * P2 + p0 + prow) * CQ + ob;
            *(h4*)(khw + row) = hv;
            *(h4*)(klw + row) = lv;
        }
    }
}

// ---------------------------------------------------------------------------
// stats: linv[b][p] = 1 / sum_q exp(energy[p][q]). HI-ONLY energy (errors
// average out in the sum; verified absmax unchanged at 0.0625 in R9).
// block 512 = 8 waves = 8 q-eighths, both p-tiles share each k load,
// 4-tile-deep k register prefetch. grid (B, P1/32) -> 2 blocks/CU.
// ---------------------------------------------------------------------------
__global__ __launch_bounds__(512) void stats_l(
        const _Float16* __restrict__ qhi,
        const _Float16* __restrict__ khi,
        float* __restrict__ linv) {
    __shared__ float lred[8][32];
    const int t = threadIdx.x;
    const int b = blockIdx.x;
    const int p0 = blockIdx.y * 32;
    const int w = t >> 6, lane = t & 63, ln = lane & 15, quad = lane >> 4;

    h8 qh0 = *(const h8*)(qhi + ((size_t)b * P1 + p0 + ln) * CQ + quad * 8);
    h8 qh1 = *(const h8*)(qhi + ((size_t)b * P1 + p0 + 16 + ln) * CQ + quad * 8);

    const _Float16* khb = khi + (size_t)b * P2 * CQ;
    const int base = w * 512;

    h8 k0 = *(const h8*)(khb + (size_t)(base + ln) * CQ + quad * 8);
    h8 k1 = *(const h8*)(khb + (size_t)(base + 16 + ln) * CQ + quad * 8);
    h8 k2 = *(const h8*)(khb + (size_t)(base + 32 + ln) * CQ + quad * 8);
    h8 k3 = *(const h8*)(khb + (size_t)(base + 48 + ln) * CQ + quad * 8);

    f4 acc0 = {0.f, 0.f, 0.f, 0.f};
    f4 acc1 = {0.f, 0.f, 0.f, 0.f};
    for (int ti = 0; ti < 32; ti += 4) {
        h8 c0 = k0, c1 = k1, c2 = k2, c3 = k3;
        if (ti + 4 < 32) {
            int q2 = base + (ti + 4) * 16 + ln;
            k0 = *(const h8*)(khb + (size_t)q2 * CQ + quad * 8);
            k1 = *(const h8*)(khb + (size_t)(q2 + 16) * CQ + quad * 8);
            k2 = *(const h8*)(khb + (size_t)(q2 + 32) * CQ + quad * 8);
            k3 = *(const h8*)(khb + (size_t)(q2 + 48) * CQ + quad * 8);
        }
        f4 z = {0.f, 0.f, 0.f, 0.f};
        f4 e00 = MFMA16(qh0, c0, z);
        f4 e10 = MFMA16(qh1, c0, z);
        f4 e01 = MFMA16(qh0, c1, z);
        f4 e11 = MFMA16(qh1, c1, z);
        f4 e02 = MFMA16(qh0, c2, z);
        f4 e12 = MFMA16(qh1, c2, z);
        f4 e03 = MFMA16(qh0, c3, z);
        f4 e13 = MFMA16(qh1, c3, z);
#pragma unroll
        for (int r = 0; r < 4; ++r) {
            acc0[r] += __expf(e00[r]) + __expf(e01[r])
                     + __expf(e02[r]) + __expf(e03[r]);
            acc1[r] += __expf(e10[r]) + __expf(e11[r])
                     + __expf(e12[r]) + __expf(e13[r]);
        }
    }
#pragma unroll
    for (int off = 1; off < 16; off <<= 1) {
#pragma unroll
        for (int r = 0; r < 4; ++r) {
            acc0[r] += __shfl_xor(acc0[r], off);
            acc1[r] += __shfl_xor(acc1[r], off);
        }
    }
    if (ln == 0) {
        *(f4*)&lred[w][quad * 4] = acc0;
        *(f4*)&lred[w][16 + quad * 4] = acc1;
    }
    __syncthreads();
    if (t < 32) {
        float s = 0.f;
#pragma unroll
        for (int i = 0; i < 8; ++i) s += lred[i][t];
        linv[(size_t)b * P1 + p0 + t] = 1.0f / s;
    }
}

// ---------------------------------------------------------------------------
// Fused attention-out GEMM — VERBATIM R8/R9 champion (~87-91 us): FULL
// C=256 x q-64, p chunks of 128, 8 waves = c-slices of 32, energy split by
// wave over 8 p-tiles, double-buffered att LDS [2][64][128] (32 KB), ONE
// barrier per chunk, v hi-only A-frags transient inside the kk loop,
// per-chunk q prefetch, setprio around GEMM MFMAs. Non-accumulator VGPR
// set fits 64 (acc[2][4] in AGPRs) -> no spill.
// grid 512 = (8b x 64qt), block 512 -> 2 blocks/CU = 16 waves/CU.
// ---------------------------------------------------------------------------
__global__ __launch_bounds__(512, 4) void attn_gemm(
        const _Float16* __restrict__ qhi, const _Float16* __restrict__ qlo,
        const _Float16* __restrict__ khi, const _Float16* __restrict__ klo,
        const _Float16* __restrict__ vhi, const float* __restrict__ linv,
        const float* __restrict__ x2, const float* __restrict__ alpha_p,
        float* __restrict__ out) {
    __shared__ _Float16 att_s[2][64][128];  // [buf][q][p], 32 KB, XOR-swizzled

    const int t  = threadIdx.x;
    const int b  = blockIdx.x & 7;          // XCD-pinned: L2 keeps v[b] slice
    const int q0 = (blockIdx.x >> 3) * 64;
    const int w  = t >> 6;                  // wave: p-tile (energy) + c-slice (gemm)
    const int lane = t & 63, ln = lane & 15, quad = lane >> 4;
    const int sw = ln & 7;

    // resident k fragments for this block's 64 q's
    h8 kh[4], kl[4];
#pragma unroll
    for (int nt = 0; nt < 4; ++nt) {
        int q = q0 + nt * 16 + ln;
        kh[nt] = *(const h8*)(khi + ((size_t)b * P2 + q) * CQ + quad * 8);
        kl[nt] = *(const h8*)(klo + ((size_t)b * P2 + q) * CQ + quad * 8);
    }

    f4 acc[2][4];
#pragma unroll
    for (int mt = 0; mt < 2; ++mt)
#pragma unroll
        for (int nt = 0; nt < 4; ++nt) acc[mt][nt] = (f4){0.f, 0.f, 0.f, 0.f};

    // prefetch q frags for chunk 0 (this wave's p-tile = w)
    h8 nqh, nql;
    {
        size_t r = ((size_t)b * P1 + w * 16 + ln) * CQ + quad * 8;
        nqh = *(const h8*)(qhi + r);
        nql = *(const h8*)(qlo + r);
    }

    const int wg   = w * 2 + (quad >> 1);               // p-granule 0..15
    const int wcol = ((wg ^ sw) << 3) + (quad & 1) * 4; // swizzled half-offset

    for (int pc = 0; pc < P1 / 128; ++pc) {
        const int p0v = pc * 128;
        h8 cqh = nqh, cql = nql;
        if (pc + 1 < P1 / 128) {
            size_t r = ((size_t)b * P1 + p0v + 128 + w * 16 + ln) * CQ + quad * 8;
            nqh = *(const h8*)(qhi + r);
            nql = *(const h8*)(qlo + r);
        }
        f4 lv = *(const f4*)(linv + (size_t)b * P1 + p0v + w * 16 + quad * 4);

        _Float16* abuf = &att_s[pc & 1][0][0];
        // ---- energy + att for p-tile w ----
#pragma unroll
        for (int nt = 0; nt < 4; ++nt) {
            f4 z = {0.f, 0.f, 0.f, 0.f};
            f4 e = MFMA16(cql, kh[nt], z);
            e = MFMA16(cqh, kl[nt], e);
            e = MFMA16(cqh, kh[nt], e);
            h4 pk;
#pragma unroll
            for (int r = 0; r < 4; ++r)
                pk[r] = (_Float16)(__expf(e[r]) * lv[r]);
            *(h4*)&abuf[(nt * 16 + ln) * 128 + wcol] = pk;
        }
        __syncthreads();

        // ---- out GEMM over this p chunk (hi-only v) ----
#pragma unroll
        for (int kk = 0; kk < 128; kk += 32) {
            h8 bf[4];
#pragma unroll
            for (int nt = 0; nt < 4; ++nt) {
                int bcol2 = (kk >> 3) + quad;
                bf[nt] = *(const h8*)&abuf[(nt * 16 + ln) * 128 + ((bcol2 ^ sw) << 3)];
            }
            h8 av[2];
#pragma unroll
            for (int mt = 0; mt < 2; ++mt) {
                size_t off = ((size_t)b * C + w * 32 + mt * 16 + ln) * P1
                           + p0v + kk + quad * 8;
                av[mt] = *(const h8*)(vhi + off);
            }
            __builtin_amdgcn_s_setprio(1);
#pragma unroll
            for (int mt = 0; mt < 2; ++mt)
#pragma unroll
                for (int nt = 0; nt < 4; ++nt)
                    acc[mt][nt] = MFMA16(av[mt], bf[nt], acc[mt][nt]);
            __builtin_amdgcn_s_setprio(0);
        }
        // no second barrier: next chunk writes the other buffer; the next
        // iteration's barrier orders its writes against this chunk's reads
    }

    const float alpha = alpha_p[0];
#pragma unroll
    for (int mt = 0; mt < 2; ++mt) {
#pragma unroll
        for (int nt = 0; nt < 4; ++nt) {
            int q = q0 + nt * 16 + ln;
#pragma unroll
            for (int r = 0; r < 4; ++r) {
                int c = w * 32 + mt * 16 + quad * 4 + r;
                size_t o = ((size_t)b * C + c) * P2 + q;
                out[o] = fmaf(alpha, acc[mt][nt][r], x2[o]);
            }
        }
    }
}

// ---------------------------------------------------------------------------
extern "C" void kernel_launch(void* const* d_in, const int* in_sizes, int n_in,
                              void* d_out, int out_size, void* d_ws, size_t ws_size,
                              hipStream_t stream) {
    const float* x1    = (const float*)d_in[0];
    const float* x2    = (const float*)d_in[1];
    const float* Wq    = (const float*)d_in[2];
    const float* bq    = (const float*)d_in[3];
    const float* Wk    = (const float*)d_in[4];
    const float* bk    = (const float*)d_in[5];
    const float* Wv    = (const float*)d_in[6];
    const float* bv    = (const float*)d_in[7];
    const float* alpha = (const float*)d_in[8];
    float* out = (float*)d_out;

    _Float16* qh = (_Float16*)d_ws;                     // [B][P1][32]
    _Float16* ql = qh + (size_t)B * P1 * CQ;
    _Float16* kh = ql + (size_t)B * P1 * CQ;            // [B][P2][32]
    _Float16* kl = kh + (size_t)B * P2 * CQ;
    _Float16* vh = kl + (size_t)B * P2 * CQ;            // [B][C][P1]
    _Float16* wqh = vh + (size_t)B * C * P1;            // [32][256]
    _Float16* wql = wqh + CQ * C;
    _Float16* wkh = wql + CQ * C;
    _Float16* wkl = wkh + CQ * C;
    _Float16* wvh = wkl + CQ * C;                       // [256][256]
    float*    li  = (float*)(wvh + C * C);              // [B][P1]

    prep_w<<<dim3(32), 256, 0, stream>>>(Wq, Wk, Wv, wqh, wql, wkh, wkl, wvh);
    prep_qkv<<<dim3(B, P1 / 32 + P2 / 32), 256, 0, stream>>>(
        x1, x2, wqh, wql, wvh, wkh, wkl, bq, bv, bk, qh, ql, vh, kh, kl);
    stats_l<<<dim3(B, P1 / 32), 512, 0, stream>>>(qh, kh, li);
    attn_gemm<<<dim3(512), 512, 0, stream>>>(qh, ql, kh, kl, vh, li, x2, alpha, out);
}

// Round 11
// 224.426 us; speedup vs baseline: 1.0141x; 1.0141x over previous
//
#include <hip/hip_runtime.h>

#define B 8
#define C 256
#define P1 2048
#define P2 4096
#define CQ 32

typedef _Float16 h8 __attribute__((ext_vector_type(8)));
typedef _Float16 h4 __attribute__((ext_vector_type(4)));
typedef float f4 __attribute__((ext_vector_type(4)));

#define MFMA16(a, b, c) __builtin_amdgcn_mfma_f32_16x16x32_f16(a, b, c, 0, 0, 0)

// ---------------------------------------------------------------------------
// Convert weights to f16 hi/lo once. grid 32 x 256.
// ---------------------------------------------------------------------------
__global__ void prep_w(const float* __restrict__ Wq, const float* __restrict__ Wk,
                       const float* __restrict__ Wv,
                       _Float16* __restrict__ Wqh, _Float16* __restrict__ Wql,
                       _Float16* __restrict__ Wkh, _Float16* __restrict__ Wkl,
                       _Float16* __restrict__ Wvh) {
    const int i = blockIdx.x * 256 + threadIdx.x;
    if (i < CQ * C) {
        float a = Wq[i]; _Float16 h = (_Float16)a;
        Wqh[i] = h; Wql[i] = (_Float16)(a - (float)h);
        float b2 = Wk[i]; _Float16 h2 = (_Float16)b2;
        Wkh[i] = h2; Wkl[i] = (_Float16)(b2 - (float)h2);
    }
    for (int j = i; j < C * C; j += 32 * 256)
        Wvh[j] = (_Float16)Wv[j];
}

// ---------------------------------------------------------------------------
// prep_qkv: merged prep1+prep2. blockIdx.y < 64 -> x1 tile: q (f16, computed
// via 3-pass hi/lo weights in fp32 then rounded once) + v (hi, single-pass).
// blockIdx.y >= 64 -> x2 tile: k (same). q/k LO outputs are DEAD now (attn
// and stats are both hi-only) -> no lo pack/stores. x staged hi/lo in LDS
// [32][264] once (b128-aligned, conflict-free). grid (B, 192), block 256.
// ---------------------------------------------------------------------------
__global__ __launch_bounds__(256) void prep_qkv(
        const float* __restrict__ x1, const float* __restrict__ x2,
        const _Float16* __restrict__ Wqh, const _Float16* __restrict__ Wql,
        const _Float16* __restrict__ Wvh,
        const _Float16* __restrict__ Wkh, const _Float16* __restrict__ Wkl,
        const float* __restrict__ bq, const float* __restrict__ bv,
        const float* __restrict__ bk,
        _Float16* __restrict__ qhw, _Float16* __restrict__ vhw,
        _Float16* __restrict__ khw) {
    __shared__ _Float16 xh[32][264];
    __shared__ _Float16 xl[32][264];
    const int t = threadIdx.x;
    const int b = blockIdx.x;
    const int y = blockIdx.y;
    const bool is1 = (y < P1 / 32);
    const int p0 = (is1 ? y : y - P1 / 32) * 32;
    const float* xb = is1 ? x1 + (size_t)b * C * P1 : x2 + (size_t)b * C * P2;
    const int ps = is1 ? P1 : P2;

    {   // stage [256c][32p] -> LDS hi/lo [p][c]; b128 loads (4 consecutive p)
        const int pl4 = t & 7, cb = t >> 3;
#pragma unroll
        for (int i = 0; i < 8; ++i) {
            const int c = cb + i * 32;
            f4 v = *(const f4*)&xb[(size_t)c * ps + p0 + pl4 * 4];
#pragma unroll
            for (int r = 0; r < 4; ++r) {
                float xv = v[r];
                _Float16 hh = (_Float16)xv;
                xh[pl4 * 4 + r][c] = hh;
                xl[pl4 * 4 + r][c] = (_Float16)(xv - (float)hh);
            }
        }
    }
    __syncthreads();

    const int w = t >> 6, lane = t & 63, ln = lane & 15, quad = lane >> 4;
    const int nh = w & 1, ch = w >> 1;
    const int prow = nh * 16 + ln;

    if (is1) {
        // ---- q (3-pass hi/lo weights, fp32 acc) + v (1-pass hi) ----
        f4 accv[8];
#pragma unroll
        for (int mt = 0; mt < 8; ++mt) accv[mt] = (f4){0.f, 0.f, 0.f, 0.f};
        f4 accq = {0.f, 0.f, 0.f, 0.f};

        for (int ks = 0; ks < 8; ++ks) {
            const int c0 = ks * 32 + quad * 8;
            h8 bh = *(const h8*)&xh[prow][c0];
            h8 bl = *(const h8*)&xl[prow][c0];
#pragma unroll
            for (int mt = 0; mt < 8; ++mt) {
                h8 a = *(const h8*)&Wvh[(size_t)((ch * 8 + mt) * 16 + ln) * C + c0];
                accv[mt] = MFMA16(a, bh, accv[mt]);
            }
            {
                h8 aqh = *(const h8*)&Wqh[(size_t)(ch * 16 + ln) * C + c0];
                h8 aql = *(const h8*)&Wql[(size_t)(ch * 16 + ln) * C + c0];
                accq = MFMA16(aql, bh, accq);
                accq = MFMA16(aqh, bl, accq);
                accq = MFMA16(aqh, bh, accq);
            }
        }
        // v epilogue: C-frag col=p(ln), row=c(quad*4+r)
#pragma unroll
        for (int mt = 0; mt < 8; ++mt) {
            int cb2 = (ch * 8 + mt) * 16 + quad * 4;
            f4 bvv = *(const f4*)&bv[cb2];
#pragma unroll
            for (int r = 0; r < 4; ++r)
                vhw[((size_t)b * C + cb2 + r) * P1 + p0 + prow] =
                    (_Float16)(accv[mt][r] + bvv[r]);
        }
        // q epilogue: single f16 round (lo is dead)
        {
            int ob = ch * 16 + quad * 4;
            f4 bqv = *(const f4*)&bq[ob];
            h4 hv;
#pragma unroll
            for (int r = 0; r < 4; ++r)
                hv[r] = (_Float16)(accq[r] + bqv[r]);
            size_t row = ((size_t)b * P1 + p0 + prow) * CQ + ob;
            *(h4*)(qhw + row) = hv;
        }
    } else {
        // ---- k (3-pass hi/lo weights, fp32 acc) ----
        f4 accq = {0.f, 0.f, 0.f, 0.f};
        for (int ks = 0; ks < 8; ++ks) {
            const int c0 = ks * 32 + quad * 8;
            h8 bh = *(const h8*)&xh[prow][c0];
            h8 bl = *(const h8*)&xl[prow][c0];
            h8 akh = *(const h8*)&Wkh[(size_t)(ch * 16 + ln) * C + c0];
            h8 akl = *(const h8*)&Wkl[(size_t)(ch * 16 + ln) * C + c0];
            accq = MFMA16(akl, bh, accq);
            accq = MFMA16(akh, bl, accq);
            accq = MFMA16(akh, bh, accq);
        }
        {
            int ob = ch * 16 + quad * 4;
            f4 bkv = *(const f4*)&bk[ob];
            h4 hv;
#pragma unroll
            for (int r = 0; r < 4; ++r)
                hv[r] = (_Float16)(accq[r] + bkv[r]);
            size_t row = ((size_t)b * P2 + p0 + prow) * CQ + ob;
            *(h4*)(khw + row) = hv;
        }
    }
}

// ---------------------------------------------------------------------------
// stats: linv[b][p] = 1 / sum_q exp(energy[p][q]). HI-ONLY energy (validated
// R9/R10: absmax unchanged). block 512 = 8 waves = 8 q-eighths, both p-tiles
// share each k load, 4-tile-deep k prefetch. grid (B, P1/32) -> 2 blocks/CU.
// ---------------------------------------------------------------------------
__global__ __launch_bounds__(512) void stats_l(
        const _Float16* __restrict__ qhi,
        const _Float16* __restrict__ khi,
        float* __restrict__ linv) {
    __shared__ float lred[8][32];
    const int t = threadIdx.x;
    const int b = blockIdx.x;
    const int p0 = blockIdx.y * 32;
    const int w = t >> 6, lane = t & 63, ln = lane & 15, quad = lane >> 4;

    h8 qh0 = *(const h8*)(qhi + ((size_t)b * P1 + p0 + ln) * CQ + quad * 8);
    h8 qh1 = *(const h8*)(qhi + ((size_t)b * P1 + p0 + 16 + ln) * CQ + quad * 8);

    const _Float16* khb = khi + (size_t)b * P2 * CQ;
    const int base = w * 512;

    h8 k0 = *(const h8*)(khb + (size_t)(base + ln) * CQ + quad * 8);
    h8 k1 = *(const h8*)(khb + (size_t)(base + 16 + ln) * CQ + quad * 8);
    h8 k2 = *(const h8*)(khb + (size_t)(base + 32 + ln) * CQ + quad * 8);
    h8 k3 = *(const h8*)(khb + (size_t)(base + 48 + ln) * CQ + quad * 8);

    f4 acc0 = {0.f, 0.f, 0.f, 0.f};
    f4 acc1 = {0.f, 0.f, 0.f, 0.f};
    for (int ti = 0; ti < 32; ti += 4) {
        h8 c0 = k0, c1 = k1, c2 = k2, c3 = k3;
        if (ti + 4 < 32) {
            int q2 = base + (ti + 4) * 16 + ln;
            k0 = *(const h8*)(khb + (size_t)q2 * CQ + quad * 8);
            k1 = *(const h8*)(khb + (size_t)(q2 + 16) * CQ + quad * 8);
            k2 = *(const h8*)(khb + (size_t)(q2 + 32) * CQ + quad * 8);
            k3 = *(const h8*)(khb + (size_t)(q2 + 48) * CQ + quad * 8);
        }
        f4 z = {0.f, 0.f, 0.f, 0.f};
        f4 e00 = MFMA16(qh0, c0, z);
        f4 e10 = MFMA16(qh1, c0, z);
        f4 e01 = MFMA16(qh0, c1, z);
        f4 e11 = MFMA16(qh1, c1, z);
        f4 e02 = MFMA16(qh0, c2, z);
        f4 e12 = MFMA16(qh1, c2, z);
        f4 e03 = MFMA16(qh0, c3, z);
        f4 e13 = MFMA16(qh1, c3, z);
#pragma unroll
        for (int r = 0; r < 4; ++r) {
            acc0[r] += __expf(e00[r]) + __expf(e01[r])
                     + __expf(e02[r]) + __expf(e03[r]);
            acc1[r] += __expf(e10[r]) + __expf(e11[r])
                     + __expf(e12[r]) + __expf(e13[r]);
        }
    }
#pragma unroll
    for (int off = 1; off < 16; off <<= 1) {
#pragma unroll
        for (int r = 0; r < 4; ++r) {
            acc0[r] += __shfl_xor(acc0[r], off);
            acc1[r] += __shfl_xor(acc1[r], off);
        }
    }
    if (ln == 0) {
        *(f4*)&lred[w][quad * 4] = acc0;
        *(f4*)&lred[w][16 + quad * 4] = acc1;
    }
    __syncthreads();
    if (t < 32) {
        float s = 0.f;
#pragma unroll
        for (int i = 0; i < 8; ++i) s += lred[i][t];
        linv[(size_t)b * P1 + p0 + t] = 1.0f / s;
    }
}

// ---------------------------------------------------------------------------
// Fused attention-out GEMM — R8 champion skeleton + two linked changes:
// (1) HI-ONLY energy e = qh*kh, matching stats (self-consistent softmax of
//     the perturbed logits; errors average in the p-sum GEMM). Frees the
//     kl[4]+ql register classes: 24 VGPRs.
// (2) Those registers fund a branch-free depth-1 av software pipeline: the
//     first av pair is issued BEFORE the energy phase (L2 latency hides
//     under energy+barrier); each kk issues the next pair before its MFMAs
//     (hides under bf reads + 8 MFMA). Addresses clamped with &(P1-1) —
//     no conditional live ranges (R3's spill trap).
// Steady-state live set ~62 VGPR -> fits the allocator's 64-reg point.
// grid 512 = (8b x 64qt), block 512 -> 2 blocks/CU = 16 waves/CU.
// ---------------------------------------------------------------------------
__global__ __launch_bounds__(512, 4) void attn_gemm(
        const _Float16* __restrict__ qhi,
        const _Float16* __restrict__ khi,
        const _Float16* __restrict__ vhi, const float* __restrict__ linv,
        const float* __restrict__ x2, const float* __restrict__ alpha_p,
        float* __restrict__ out) {
    __shared__ _Float16 att_s[2][64][128];  // [buf][q][p], 32 KB, XOR-swizzled

    const int t  = threadIdx.x;
    const int b  = blockIdx.x & 7;          // XCD-pinned: L2 keeps v[b] slice
    const int q0 = (blockIdx.x >> 3) * 64;
    const int w  = t >> 6;                  // wave: p-tile (energy) + c-slice (gemm)
    const int lane = t & 63, ln = lane & 15, quad = lane >> 4;
    const int sw = ln & 7;

    // resident k fragments for this block's 64 q's (hi only, 16 VGPRs)
    h8 kh[4];
#pragma unroll
    for (int nt = 0; nt < 4; ++nt) {
        int q = q0 + nt * 16 + ln;
        kh[nt] = *(const h8*)(khi + ((size_t)b * P2 + q) * CQ + quad * 8);
    }

    f4 acc[2][4];
#pragma unroll
    for (int mt = 0; mt < 2; ++mt)
#pragma unroll
        for (int nt = 0; nt < 4; ++nt) acc[mt][nt] = (f4){0.f, 0.f, 0.f, 0.f};

    // v row bases for this wave's c-slice (quad offset folded in)
    const _Float16* vr0 = vhi + ((size_t)b * C + w * 32 + ln) * P1 + quad * 8;
    const _Float16* vr1 = vr0 + (size_t)16 * P1;

    // prefetch q frag for chunk 0 (hi only, 4 VGPRs)
    h8 nqh = *(const h8*)(qhi + ((size_t)b * P1 + w * 16 + ln) * CQ + quad * 8);

    // depth-1 av pipeline: issue chunk0/kk0 pair now (hides under energy)
    h8 avn0 = *(const h8*)(vr0);
    h8 avn1 = *(const h8*)(vr1);

    const int wg   = w * 2 + (quad >> 1);               // p-granule 0..15
    const int wcol = ((wg ^ sw) << 3) + (quad & 1) * 4; // swizzled half-offset

    for (int pc = 0; pc < P1 / 128; ++pc) {
        const int p0v = pc * 128;
        h8 cqh = nqh;
        {   // unconditional, clamped next-chunk q prefetch
            int pn = (p0v + 128) & (P1 - 1);
            nqh = *(const h8*)(qhi + ((size_t)b * P1 + pn + w * 16 + ln) * CQ
                               + quad * 8);
        }
        f4 lv = *(const f4*)(linv + (size_t)b * P1 + p0v + w * 16 + quad * 4);

        _Float16* abuf = &att_s[pc & 1][0][0];
        // ---- energy + att for p-tile w (hi-only) ----
#pragma unroll
        for (int nt = 0; nt < 4; ++nt) {
            f4 z = {0.f, 0.f, 0.f, 0.f};
            f4 e = MFMA16(cqh, kh[nt], z);
            h4 pk;
#pragma unroll
            for (int r = 0; r < 4; ++r)
                pk[r] = (_Float16)(__expf(e[r]) * lv[r]);
            *(h4*)&abuf[(nt * 16 + ln) * 128 + wcol] = pk;
        }
        __syncthreads();

        // ---- out GEMM over this p chunk; av rotated depth-1 ----
#pragma unroll
        for (int kk = 0; kk < 4; ++kk) {
            h8 av0 = avn0, av1 = avn1;
            {   // issue next pair: kk+1 of this chunk, or next chunk's kk0
                int pnext = (p0v + (kk + 1) * 32) & (P1 - 1);
                avn0 = *(const h8*)(vr0 + pnext);
                avn1 = *(const h8*)(vr1 + pnext);
            }
            h8 bf[4];
#pragma unroll
            for (int nt = 0; nt < 4; ++nt) {
                int bcol2 = kk * 4 + quad;
                bf[nt] = *(const h8*)&abuf[(nt * 16 + ln) * 128 + ((bcol2 ^ sw) << 3)];
            }
            __builtin_amdgcn_s_setprio(1);
#pragma unroll
            for (int nt = 0; nt < 4; ++nt)
                acc[0][nt] = MFMA16(av0, bf[nt], acc[0][nt]);
#pragma unroll
            for (int nt = 0; nt < 4; ++nt)
                acc[1][nt] = MFMA16(av1, bf[nt], acc[1][nt]);
            __builtin_amdgcn_s_setprio(0);
        }
        // no second barrier: next chunk writes the other buffer; the next
        // iteration's barrier orders its writes against this chunk's reads
    }

    const float alpha = alpha_p[0];
#pragma unroll
    for (int mt = 0; mt < 2; ++mt) {
#pragma unroll
        for (int nt = 0; nt < 4; ++nt) {
            int q = q0 + nt * 16 + ln;
#pragma unroll
            for (int r = 0; r < 4; ++r) {
                int c = w * 32 + mt * 16 + quad * 4 + r;
                size_t o = ((size_t)b * C + c) * P2 + q;
                out[o] = fmaf(alpha, acc[mt][nt][r], x2[o]);
            }
        }
    }
}

// ---------------------------------------------------------------------------
extern "C" void kernel_launch(void* const* d_in, const int* in_sizes, int n_in,
                              void* d_out, int out_size, void* d_ws, size_t ws_size,
                              hipStream_t stream) {
    const float* x1    = (const float*)d_in[0];
    const float* x2    = (const float*)d_in[1];
    const float* Wq    = (const float*)d_in[2];
    const float* bq    = (const float*)d_in[3];
    const float* Wk    = (const float*)d_in[4];
    const float* bk    = (const float*)d_in[5];
    const float* Wv    = (const float*)d_in[6];
    const float* bv    = (const float*)d_in[7];
    const float* alpha = (const float*)d_in[8];
    float* out = (float*)d_out;

    _Float16* qh = (_Float16*)d_ws;                     // [B][P1][32]
    _Float16* ql = qh + (size_t)B * P1 * CQ;            // (unused, layout kept)
    _Float16* kh = ql + (size_t)B * P1 * CQ;            // [B][P2][32]
    _Float16* kl = kh + (size_t)B * P2 * CQ;            // (unused, layout kept)
    _Float16* vh = kl + (size_t)B * P2 * CQ;            // [B][C][P1]
    _Float16* wqh = vh + (size_t)B * C * P1;            // [32][256]
    _Float16* wql = wqh + CQ * C;
    _Float16* wkh = wql + CQ * C;
    _Float16* wkl = wkh + CQ * C;
    _Float16* wvh = wkl + CQ * C;                       // [256][256]
    float*    li  = (float*)(wvh + C * C);              // [B][P1]

    prep_w<<<dim3(32), 256, 0, stream>>>(Wq, Wk, Wv, wqh, wql, wkh, wkl, wvh);
    prep_qkv<<<dim3(B, P1 / 32 + P2 / 32), 256, 0, stream>>>(
        x1, x2, wqh, wql, wvh, wkh, wkl, bq, bv, bk, qh, vh, kh);
    stats_l<<<dim3(B, P1 / 32), 512, 0, stream>>>(qh, kh, li);
    attn_gemm<<<dim3(512), 512, 0, stream>>>(qh, kh, vh, li, x2, alpha, out);
}

// Round 12
// 223.885 us; speedup vs baseline: 1.0166x; 1.0024x over previous
//
#include <hip/hip_runtime.h>

#define B 8
#define C 256
#define P1 2048
#define P2 4096
#define CQ 32

typedef _Float16 h8 __attribute__((ext_vector_type(8)));
typedef _Float16 h4 __attribute__((ext_vector_type(4)));
typedef float f4 __attribute__((ext_vector_type(4)));

#define MFMA16(a, b, c) __builtin_amdgcn_mfma_f32_16x16x32_f16(a, b, c, 0, 0, 0)

// ---------------------------------------------------------------------------
// Convert weights to f16 hi/lo once. grid 32 x 256.
// ---------------------------------------------------------------------------
__global__ void prep_w(const float* __restrict__ Wq, const float* __restrict__ Wk,
                       const float* __restrict__ Wv,
                       _Float16* __restrict__ Wqh, _Float16* __restrict__ Wql,
                       _Float16* __restrict__ Wkh, _Float16* __restrict__ Wkl,
                       _Float16* __restrict__ Wvh) {
    const int i = blockIdx.x * 256 + threadIdx.x;
    if (i < CQ * C) {
        float a = Wq[i]; _Float16 h = (_Float16)a;
        Wqh[i] = h; Wql[i] = (_Float16)(a - (float)h);
        float b2 = Wk[i]; _Float16 h2 = (_Float16)b2;
        Wkh[i] = h2; Wkl[i] = (_Float16)(b2 - (float)h2);
    }
    for (int j = i; j < C * C; j += 32 * 256)
        Wvh[j] = (_Float16)Wv[j];
}

// ---------------------------------------------------------------------------
// prep_qkv: merged prep1+prep2. blockIdx.y < 64 -> x1 tile: q (f16, 3-pass
// hi/lo weights, fp32 acc, single round) + v (hi, 1-pass). blockIdx.y >= 64
// -> x2 tile: k (same as q). x staged hi/lo in LDS [32][264] once.
// grid (B, 192), block 256.
// ---------------------------------------------------------------------------
__global__ __launch_bounds__(256) void prep_qkv(
        const float* __restrict__ x1, const float* __restrict__ x2,
        const _Float16* __restrict__ Wqh, const _Float16* __restrict__ Wql,
        const _Float16* __restrict__ Wvh,
        const _Float16* __restrict__ Wkh, const _Float16* __restrict__ Wkl,
        const float* __restrict__ bq, const float* __restrict__ bv,
        const float* __restrict__ bk,
        _Float16* __restrict__ qhw, _Float16* __restrict__ vhw,
        _Float16* __restrict__ khw) {
    __shared__ _Float16 xh[32][264];
    __shared__ _Float16 xl[32][264];
    const int t = threadIdx.x;
    const int b = blockIdx.x;
    const int y = blockIdx.y;
    const bool is1 = (y < P1 / 32);
    const int p0 = (is1 ? y : y - P1 / 32) * 32;
    const float* xb = is1 ? x1 + (size_t)b * C * P1 : x2 + (size_t)b * C * P2;
    const int ps = is1 ? P1 : P2;

    {   // stage [256c][32p] -> LDS hi/lo [p][c]; b128 loads (4 consecutive p)
        const int pl4 = t & 7, cb = t >> 3;
#pragma unroll
        for (int i = 0; i < 8; ++i) {
            const int c = cb + i * 32;
            f4 v = *(const f4*)&xb[(size_t)c * ps + p0 + pl4 * 4];
#pragma unroll
            for (int r = 0; r < 4; ++r) {
                float xv = v[r];
                _Float16 hh = (_Float16)xv;
                xh[pl4 * 4 + r][c] = hh;
                xl[pl4 * 4 + r][c] = (_Float16)(xv - (float)hh);
            }
        }
    }
    __syncthreads();

    const int w = t >> 6, lane = t & 63, ln = lane & 15, quad = lane >> 4;
    const int nh = w & 1, ch = w >> 1;
    const int prow = nh * 16 + ln;

    if (is1) {
        // ---- q (3-pass hi/lo weights, fp32 acc) + v (1-pass hi) ----
        f4 accv[8];
#pragma unroll
        for (int mt = 0; mt < 8; ++mt) accv[mt] = (f4){0.f, 0.f, 0.f, 0.f};
        f4 accq = {0.f, 0.f, 0.f, 0.f};

        for (int ks = 0; ks < 8; ++ks) {
            const int c0 = ks * 32 + quad * 8;
            h8 bh = *(const h8*)&xh[prow][c0];
            h8 bl = *(const h8*)&xl[prow][c0];
#pragma unroll
            for (int mt = 0; mt < 8; ++mt) {
                h8 a = *(const h8*)&Wvh[(size_t)((ch * 8 + mt) * 16 + ln) * C + c0];
                accv[mt] = MFMA16(a, bh, accv[mt]);
            }
            {
                h8 aqh = *(const h8*)&Wqh[(size_t)(ch * 16 + ln) * C + c0];
                h8 aql = *(const h8*)&Wql[(size_t)(ch * 16 + ln) * C + c0];
                accq = MFMA16(aql, bh, accq);
                accq = MFMA16(aqh, bl, accq);
                accq = MFMA16(aqh, bh, accq);
            }
        }
        // v epilogue: C-frag col=p(ln), row=c(quad*4+r)
#pragma unroll
        for (int mt = 0; mt < 8; ++mt) {
            int cb2 = (ch * 8 + mt) * 16 + quad * 4;
            f4 bvv = *(const f4*)&bv[cb2];
#pragma unroll
            for (int r = 0; r < 4; ++r)
                vhw[((size_t)b * C + cb2 + r) * P1 + p0 + prow] =
                    (_Float16)(accv[mt][r] + bvv[r]);
        }
        // q epilogue: single f16 round
        {
            int ob = ch * 16 + quad * 4;
            f4 bqv = *(const f4*)&bq[ob];
            h4 hv;
#pragma unroll
            for (int r = 0; r < 4; ++r)
                hv[r] = (_Float16)(accq[r] + bqv[r]);
            size_t row = ((size_t)b * P1 + p0 + prow) * CQ + ob;
            *(h4*)(qhw + row) = hv;
        }
    } else {
        // ---- k (3-pass hi/lo weights, fp32 acc) ----
        f4 accq = {0.f, 0.f, 0.f, 0.f};
        for (int ks = 0; ks < 8; ++ks) {
            const int c0 = ks * 32 + quad * 8;
            h8 bh = *(const h8*)&xh[prow][c0];
            h8 bl = *(const h8*)&xl[prow][c0];
            h8 akh = *(const h8*)&Wkh[(size_t)(ch * 16 + ln) * C + c0];
            h8 akl = *(const h8*)&Wkl[(size_t)(ch * 16 + ln) * C + c0];
            accq = MFMA16(akl, bh, accq);
            accq = MFMA16(akh, bl, accq);
            accq = MFMA16(akh, bh, accq);
        }
        {
            int ob = ch * 16 + quad * 4;
            f4 bkv = *(const f4*)&bk[ob];
            h4 hv;
#pragma unroll
            for (int r = 0; r < 4; ++r)
                hv[r] = (_Float16)(accq[r] + bkv[r]);
            size_t row = ((size_t)b * P2 + p0 + prow) * CQ + ob;
            *(h4*)(khw + row) = hv;
        }
    }
}

// ---------------------------------------------------------------------------
// stats: linv[b][p] = 1 / sum_q exp(energy[p][q]). HI-ONLY energy (validated
// R9-R11: absmax unchanged). block 512 = 8 waves = 8 q-eighths, both p-tiles
// share each k load, 4-tile-deep k prefetch. grid (B, P1/32) -> 2 blocks/CU.
// ---------------------------------------------------------------------------
__global__ __launch_bounds__(512) void stats_l(
        const _Float16* __restrict__ qhi,
        const _Float16* __restrict__ khi,
        float* __restrict__ linv) {
    __shared__ float lred[8][32];
    const int t = threadIdx.x;
    const int b = blockIdx.x;
    const int p0 = blockIdx.y * 32;
    const int w = t >> 6, lane = t & 63, ln = lane & 15, quad = lane >> 4;

    h8 qh0 = *(const h8*)(qhi + ((size_t)b * P1 + p0 + ln) * CQ + quad * 8);
    h8 qh1 = *(const h8*)(qhi + ((size_t)b * P1 + p0 + 16 + ln) * CQ + quad * 8);

    const _Float16* khb = khi + (size_t)b * P2 * CQ;
    const int base = w * 512;

    h8 k0 = *(const h8*)(khb + (size_t)(base + ln) * CQ + quad * 8);
    h8 k1 = *(const h8*)(khb + (size_t)(base + 16 + ln) * CQ + quad * 8);
    h8 k2 = *(const h8*)(khb + (size_t)(base + 32 + ln) * CQ + quad * 8);
    h8 k3 = *(const h8*)(khb + (size_t)(base + 48 + ln) * CQ + quad * 8);

    f4 acc0 = {0.f, 0.f, 0.f, 0.f};
    f4 acc1 = {0.f, 0.f, 0.f, 0.f};
    for (int ti = 0; ti < 32; ti += 4) {
        h8 c0 = k0, c1 = k1, c2 = k2, c3 = k3;
        if (ti + 4 < 32) {
            int q2 = base + (ti + 4) * 16 + ln;
            k0 = *(const h8*)(khb + (size_t)q2 * CQ + quad * 8);
            k1 = *(const h8*)(khb + (size_t)(q2 + 16) * CQ + quad * 8);
            k2 = *(const h8*)(khb + (size_t)(q2 + 32) * CQ + quad * 8);
            k3 = *(const h8*)(khb + (size_t)(q2 + 48) * CQ + quad * 8);
        }
        f4 z = {0.f, 0.f, 0.f, 0.f};
        f4 e00 = MFMA16(qh0, c0, z);
        f4 e10 = MFMA16(qh1, c0, z);
        f4 e01 = MFMA16(qh0, c1, z);
        f4 e11 = MFMA16(qh1, c1, z);
        f4 e02 = MFMA16(qh0, c2, z);
        f4 e12 = MFMA16(qh1, c2, z);
        f4 e03 = MFMA16(qh0, c3, z);
        f4 e13 = MFMA16(qh1, c3, z);
#pragma unroll
        for (int r = 0; r < 4; ++r) {
            acc0[r] += __expf(e00[r]) + __expf(e01[r])
                     + __expf(e02[r]) + __expf(e03[r]);
            acc1[r] += __expf(e10[r]) + __expf(e11[r])
                     + __expf(e12[r]) + __expf(e13[r]);
        }
    }
#pragma unroll
    for (int off = 1; off < 16; off <<= 1) {
#pragma unroll
        for (int r = 0; r < 4; ++r) {
            acc0[r] += __shfl_xor(acc0[r], off);
            acc1[r] += __shfl_xor(acc1[r], off);
        }
    }
    if (ln == 0) {
        *(f4*)&lred[w][quad * 4] = acc0;
        *(f4*)&lred[w][16 + quad * 4] = acc1;
    }
    __syncthreads();
    if (t < 32) {
        float s = 0.f;
#pragma unroll
        for (int i = 0; i < 8; ++i) s += lred[i][t];
        linv[(size_t)b * P1 + p0 + t] = 1.0f / s;
    }
}

// ---------------------------------------------------------------------------
// Fused attention-out GEMM — R11 structure (hi-only energy, depth-1 av
// rotate, clamped prefetch) with p-chunk 256: HALF the barriers (8/block)
// and 8 kk-steps of GEMM per barrier. This retries R4's barrier-halving
// under the post-R11 register footprint: hi-only energy removed kl(16)+
// ql(8) so the chunk-256 live set (~kh 16 + nqh 8 + avn 8 + bf 16 + addr)
// now fits the allocator's 64-VGPR point — R4's spill cause is gone.
// LDS 2 x [64][256] = 64 KB -> still 2 blocks/CU. Energy: each wave does
// 2 p-tiles (w*16 and 128+w*16). grid 512 = (8b x 64qt), block 512.
// ---------------------------------------------------------------------------
__global__ __launch_bounds__(512, 4) void attn_gemm(
        const _Float16* __restrict__ qhi,
        const _Float16* __restrict__ khi,
        const _Float16* __restrict__ vhi, const float* __restrict__ linv,
        const float* __restrict__ x2, const float* __restrict__ alpha_p,
        float* __restrict__ out) {
    __shared__ _Float16 att_s[2][64][256];  // [buf][q][p], 64 KB, XOR-swizzled

    const int t  = threadIdx.x;
    const int b  = blockIdx.x & 7;          // XCD-pinned: L2 keeps v[b] slice
    const int q0 = (blockIdx.x >> 3) * 64;
    const int w  = t >> 6;                  // wave: 2 p-tiles (energy) + c-slice
    const int lane = t & 63, ln = lane & 15, quad = lane >> 4;
    const int sw = ln & 7;

    // resident k fragments for this block's 64 q's (hi only, 16 VGPRs)
    h8 kh[4];
#pragma unroll
    for (int nt = 0; nt < 4; ++nt) {
        int q = q0 + nt * 16 + ln;
        kh[nt] = *(const h8*)(khi + ((size_t)b * P2 + q) * CQ + quad * 8);
    }

    f4 acc[2][4];
#pragma unroll
    for (int mt = 0; mt < 2; ++mt)
#pragma unroll
        for (int nt = 0; nt < 4; ++nt) acc[mt][nt] = (f4){0.f, 0.f, 0.f, 0.f};

    // v row bases for this wave's c-slice (quad offset folded in)
    const _Float16* vr0 = vhi + ((size_t)b * C + w * 32 + ln) * P1 + quad * 8;
    const _Float16* vr1 = vr0 + (size_t)16 * P1;

    // q frags for chunk 0 (2 p-tiles: w*16 and 128+w*16; 8 VGPRs)
    h8 nqh0 = *(const h8*)(qhi + ((size_t)b * P1 + w * 16 + ln) * CQ + quad * 8);
    h8 nqh1 = *(const h8*)(qhi + ((size_t)b * P1 + 128 + w * 16 + ln) * CQ + quad * 8);

    // depth-1 av pipeline: issue chunk0/kk0 pair now (hides under energy)
    h8 avn0 = *(const h8*)(vr0);
    h8 avn1 = *(const h8*)(vr1);

    for (int pc = 0; pc < P1 / 256; ++pc) {
        const int p0v = pc * 256;
        h8 cqh0 = nqh0, cqh1 = nqh1;
        {   // unconditional, clamped next-chunk q prefetch
            int pn = (p0v + 256) & (P1 - 1);
            nqh0 = *(const h8*)(qhi + ((size_t)b * P1 + pn + w * 16 + ln) * CQ
                                + quad * 8);
            nqh1 = *(const h8*)(qhi + ((size_t)b * P1 + pn + 128 + w * 16 + ln) * CQ
                                + quad * 8);
        }

        _Float16* abuf = &att_s[pc & 1][0][0];
        // ---- energy + att for p-tiles w*16 and 128+w*16 (hi-only) ----
#pragma unroll
        for (int pt = 0; pt < 2; ++pt) {
            h8 cqh = pt ? cqh1 : cqh0;
            f4 lv = *(const f4*)(linv + (size_t)b * P1 + p0v + pt * 128
                                 + w * 16 + quad * 4);
            const int gb  = (pt << 4) + (w << 1) + (quad >> 1); // granule 0..31
            const int col = ((gb ^ sw) << 3) + ((quad & 1) << 2);
#pragma unroll
            for (int nt = 0; nt < 4; ++nt) {
                f4 z = {0.f, 0.f, 0.f, 0.f};
                f4 e = MFMA16(cqh, kh[nt], z);
                h4 pk;
#pragma unroll
                for (int r = 0; r < 4; ++r)
                    pk[r] = (_Float16)(__expf(e[r]) * lv[r]);
                *(h4*)&abuf[(nt * 16 + ln) * 256 + col] = pk;
            }
        }
        __syncthreads();

        // ---- out GEMM over this 256-p chunk; av rotated depth-1 ----
#pragma unroll
        for (int kk = 0; kk < 8; ++kk) {
            h8 av0 = avn0, av1 = avn1;
            {   // issue next pair: kk+1 of this chunk, or next chunk's kk0
                int pnext = (p0v + (kk + 1) * 32) & (P1 - 1);
                avn0 = *(const h8*)(vr0 + pnext);
                avn1 = *(const h8*)(vr1 + pnext);
            }
            h8 bf[4];
#pragma unroll
            for (int nt = 0; nt < 4; ++nt) {
                int g = kk * 4 + quad;              // granule 0..31
                bf[nt] = *(const h8*)&abuf[(nt * 16 + ln) * 256 + ((g ^ sw) << 3)];
            }
            __builtin_amdgcn_s_setprio(1);
#pragma unroll
            for (int nt = 0; nt < 4; ++nt)
                acc[0][nt] = MFMA16(av0, bf[nt], acc[0][nt]);
#pragma unroll
            for (int nt = 0; nt < 4; ++nt)
                acc[1][nt] = MFMA16(av1, bf[nt], acc[1][nt]);
            __builtin_amdgcn_s_setprio(0);
        }
        // no second barrier: next chunk writes the other buffer; the next
        // iteration's barrier orders its writes against this chunk's reads
    }

    const float alpha = alpha_p[0];
#pragma unroll
    for (int mt = 0; mt < 2; ++mt) {
#pragma unroll
        for (int nt = 0; nt < 4; ++nt) {
            int q = q0 + nt * 16 + ln;
#pragma unroll
            for (int r = 0; r < 4; ++r) {
                int c = w * 32 + mt * 16 + quad * 4 + r;
                size_t o = ((size_t)b * C + c) * P2 + q;
                out[o] = fmaf(alpha, acc[mt][nt][r], x2[o]);
            }
        }
    }
}

// ---------------------------------------------------------------------------
extern "C" void kernel_launch(void* const* d_in, const int* in_sizes, int n_in,
                              void* d_out, int out_size, void* d_ws, size_t ws_size,
                              hipStream_t stream) {
    const float* x1    = (const float*)d_in[0];
    const float* x2    = (const float*)d_in[1];
    const float* Wq    = (const float*)d_in[2];
    const float* bq    = (const float*)d_in[3];
    const float* Wk    = (const float*)d_in[4];
    const float* bk    = (const float*)d_in[5];
    const float* Wv    = (const float*)d_in[6];
    const float* bv    = (const float*)d_in[7];
    const float* alpha = (const float*)d_in[8];
    float* out = (float*)d_out;

    _Float16* qh = (_Float16*)d_ws;                     // [B][P1][32]
    _Float16* ql = qh + (size_t)B * P1 * CQ;            // (unused, layout kept)
    _Float16* kh = ql + (size_t)B * P1 * CQ;            // [B][P2][32]
    _Float16* kl = kh + (size_t)B * P2 * CQ;            // (unused, layout kept)
    _Float16* vh = kl + (size_t)B * P2 * CQ;            // [B][C][P1]
    _Float16* wqh = vh + (size_t)B * C * P1;            // [32][256]
    _Float16* wql = wqh + CQ * C;
    _Float16* wkh = wql + CQ * C;
    _Float16* wkl = wkh + CQ * C;
    _Float16* wvh = wkl + CQ * C;                       // [256][256]
    float*    li  = (float*)(wvh + C * C);              // [B][P1]

    prep_w<<<dim3(32), 256, 0, stream>>>(Wq, Wk, Wv, wqh, wql, wkh, wkl, wvh);
    prep_qkv<<<dim3(B, P1 / 32 + P2 / 32), 256, 0, stream>>>(
        x1, x2, wqh, wql, wvh, wkh, wkl, bq, bv, bk, qh, vh, kh);
    stats_l<<<dim3(B, P1 / 32), 512, 0, stream>>>(qh, kh, li);
    attn_gemm<<<dim3(512), 512, 0, stream>>>(qh, kh, vh, li, x2, alpha, out);
}